// Round 1
// baseline (1340.146 us; speedup 1.0000x reference)
//
#include <hip/hip_runtime.h>
#include <math.h>

// Problem constants (from reference): V = 1e6 nodes, D = 256, B = 32768 graphs.
// batch is SORTED -> segments are contiguous runs of rows of H.
// Wb is a uniform additive shift on scores -> cancels in softmax -> dropped (exact).

#define DIM 256           // feature dim
#define LANES 64          // wave size
// each lane owns DIM/LANES = 4 consecutive floats -> one float4 per lane per row

// Kernel 1: segment boundaries via lower_bound on sorted batch.
// seg_start[b] = first index v with batch[v] >= b, for b in [0, B]; seg_start[B] = V.
__global__ void seg_bounds_kernel(const int* __restrict__ batch, int V, int B,
                                  int* __restrict__ seg_start) {
    int b = blockIdx.x * blockDim.x + threadIdx.x;
    if (b > B) return;
    int lo = 0, hi = V;
    while (lo < hi) {
        int mid = (lo + hi) >> 1;
        if (batch[mid] < b) lo = mid + 1; else hi = mid;
    }
    seg_start[b] = lo;
}

// Kernel 2: one wave per segment, online-softmax weighted pooling, single pass over H.
__launch_bounds__(256)
__global__ void attn_agg_kernel(const float* __restrict__ H,
                                const float* __restrict__ Ww,
                                const int* __restrict__ seg_start,
                                float* __restrict__ out, int B) {
    const int wave = threadIdx.x >> 6;         // 4 waves per block
    const int lane = threadIdx.x & 63;
    const int b = blockIdx.x * 4 + wave;
    if (b >= B) return;

    const float4* __restrict__ H4 = (const float4*)H;
    const float4 w = ((const float4*)Ww)[lane];   // lane's slice of the weight row

    const int start = seg_start[b];
    const int end   = seg_start[b + 1];

    float m = -INFINITY;     // running max
    float l = 0.0f;          // running sum of exp
    float4 acc = make_float4(0.f, 0.f, 0.f, 0.f);  // running weighted sum (lane's 4 dims)

    int v = start;
    float4 h = (v < end) ? H4[(size_t)v * LANES + lane] : make_float4(0.f, 0.f, 0.f, 0.f);
    for (; v < end; ++v) {
        // prefetch next row while we reduce the current one
        float4 hn = (v + 1 < end) ? H4[(size_t)(v + 1) * LANES + lane] : h;

        // score = dot(H[v], Ww): per-lane partial then 64-lane butterfly reduce
        float p = h.x * w.x + h.y * w.y + h.z * w.z + h.w * w.w;
        #pragma unroll
        for (int off = 32; off > 0; off >>= 1)
            p += __shfl_xor(p, off, 64);

        // online softmax update
        float mn    = fmaxf(m, p);
        float e     = __expf(p - mn);      // weight of this row
        float scale = __expf(m - mn);      // rescale of old accum (0 on first row: m=-inf)
        l = l * scale + e;
        acc.x = acc.x * scale + e * h.x;
        acc.y = acc.y * scale + e * h.y;
        acc.z = acc.z * scale + e * h.z;
        acc.w = acc.w * scale + e * h.w;
        m = mn;

        h = hn;
    }

    // empty segment -> l == 0 -> write zeros (matches reference: segment_sum gives 0)
    const float inv = (l > 0.0f) ? (1.0f / l) : 0.0f;
    float4 o = make_float4(acc.x * inv, acc.y * inv, acc.z * inv, acc.w * inv);
    ((float4*)out)[(size_t)b * LANES + lane] = o;
}

extern "C" void kernel_launch(void* const* d_in, const int* in_sizes, int n_in,
                              void* d_out, int out_size, void* d_ws, size_t ws_size,
                              hipStream_t stream) {
    const float* H     = (const float*)d_in[0];
    const int*   batch = (const int*)d_in[1];
    const float* Ww    = (const float*)d_in[2];
    // d_in[3] (Wb) intentionally unused: uniform score shift cancels in softmax.

    const int V = in_sizes[1];
    const int B = out_size / DIM;

    int* seg_start = (int*)d_ws;   // (B+1) ints

    {
        int n = B + 1;
        int threads = 256;
        int blocks = (n + threads - 1) / threads;
        seg_bounds_kernel<<<blocks, threads, 0, stream>>>(batch, V, B, seg_start);
    }
    {
        int threads = 256;                 // 4 waves per block, 1 segment per wave
        int blocks = (B + 3) / 4;
        attn_agg_kernel<<<blocks, threads, 0, stream>>>(H, Ww, seg_start, (float*)d_out, B);
    }
}

// Round 2
// 1294.665 us; speedup vs baseline: 1.0351x; 1.0351x over previous
//
#include <hip/hip_runtime.h>
#include <math.h>

// V = 1e6 nodes, D = 256, B = 32768 graphs. batch is SORTED -> contiguous segments.
// Wb is a uniform score shift -> cancels in softmax -> dropped (exact).

#define DIM 256
#define LANES 64
#define CHUNK 8   // rows processed per inner iteration (MLP + interleaved reductions)

// Kernel 1: segment boundaries via lower_bound on sorted batch.
__global__ void seg_bounds_kernel(const int* __restrict__ batch, int V, int B,
                                  int* __restrict__ seg_start) {
    int b = blockIdx.x * blockDim.x + threadIdx.x;
    if (b > B) return;
    int lo = 0, hi = V;
    while (lo < hi) {
        int mid = (lo + hi) >> 1;
        if (batch[mid] < b) lo = mid + 1; else hi = mid;
    }
    seg_start[b] = lo;
}

// Kernel 2: one wave per segment, online softmax, CHUNK rows per iteration.
// Lane i owns dims [4i,4i+4) as one float4 -> each row is one coalesced 1KB wave load.
__launch_bounds__(256)
__global__ void attn_agg_kernel(const float* __restrict__ H,
                                const float* __restrict__ Ww,
                                const int* __restrict__ seg_start,
                                float* __restrict__ out, int B) {
    const int wave = threadIdx.x >> 6;
    const int lane = threadIdx.x & 63;
    const int b = blockIdx.x * 4 + wave;
    if (b >= B) return;

    const float4* __restrict__ H4 = (const float4*)H;
    const float4 w = ((const float4*)Ww)[lane];

    const int start = seg_start[b];
    const int end   = seg_start[b + 1];

    float m = -INFINITY;
    float l = 0.0f;
    float4 acc = make_float4(0.f, 0.f, 0.f, 0.f);

    for (int v = start; v < end; v += CHUNK) {
        // 1) issue CHUNK independent loads (clamped addresses for the tail; masked later)
        float4 h[CHUNK];
        #pragma unroll
        for (int k = 0; k < CHUNK; ++k) {
            int idx = (v + k < end) ? (v + k) : (end - 1);
            h[k] = H4[(size_t)idx * LANES + lane];
        }

        // 2) per-lane partial dots
        float p[CHUNK];
        #pragma unroll
        for (int k = 0; k < CHUNK; ++k)
            p[k] = h[k].x * w.x + h[k].y * w.y + h[k].z * w.z + h[k].w * w.w;

        // 3) CHUNK interleaved 64-lane butterfly reductions (independent chains)
        #pragma unroll
        for (int off = 32; off > 0; off >>= 1) {
            #pragma unroll
            for (int k = 0; k < CHUNK; ++k)
                p[k] += __shfl_xor(p[k], off, 64);
        }

        // 4) mask tail rows
        #pragma unroll
        for (int k = 0; k < CHUNK; ++k)
            if (v + k >= end) p[k] = -INFINITY;

        // 5) one online-softmax combine per chunk
        float mc = p[0];
        #pragma unroll
        for (int k = 1; k < CHUNK; ++k) mc = fmaxf(mc, p[k]);
        float mn = fmaxf(m, mc);
        float so = __expf(m - mn);           // old-accumulator rescale (0 on first chunk)

        float e[CHUNK];
        float es = 0.0f;
        #pragma unroll
        for (int k = 0; k < CHUNK; ++k) { e[k] = __expf(p[k] - mn); es += e[k]; }

        float4 a2 = make_float4(0.f, 0.f, 0.f, 0.f);
        #pragma unroll
        for (int k = 0; k < CHUNK; ++k) {
            a2.x += e[k] * h[k].x;
            a2.y += e[k] * h[k].y;
            a2.z += e[k] * h[k].z;
            a2.w += e[k] * h[k].w;
        }

        l     = l * so + es;
        acc.x = acc.x * so + a2.x;
        acc.y = acc.y * so + a2.y;
        acc.z = acc.z * so + a2.z;
        acc.w = acc.w * so + a2.w;
        m = mn;
    }

    const float inv = (l > 0.0f) ? (1.0f / l) : 0.0f;   // empty segment -> zeros
    float4 o = make_float4(acc.x * inv, acc.y * inv, acc.z * inv, acc.w * inv);
    ((float4*)out)[(size_t)b * LANES + lane] = o;
}

extern "C" void kernel_launch(void* const* d_in, const int* in_sizes, int n_in,
                              void* d_out, int out_size, void* d_ws, size_t ws_size,
                              hipStream_t stream) {
    const float* H     = (const float*)d_in[0];
    const int*   batch = (const int*)d_in[1];
    const float* Ww    = (const float*)d_in[2];
    // d_in[3] (Wb) unused: uniform score shift cancels in softmax.

    const int V = in_sizes[1];
    const int B = out_size / DIM;

    int* seg_start = (int*)d_ws;   // (B+1) ints

    {
        int n = B + 1;
        int threads = 256;
        int blocks = (n + threads - 1) / threads;
        seg_bounds_kernel<<<blocks, threads, 0, stream>>>(batch, V, B, seg_start);
    }
    {
        int threads = 256;                 // 4 waves per block, 1 segment per wave
        int blocks = (B + 3) / 4;
        attn_agg_kernel<<<blocks, threads, 0, stream>>>(H, Ww, seg_start, (float*)d_out, B);
    }
}